// Round 4
// baseline (8239.986 us; speedup 1.0000x reference)
//
#include <hip/hip_runtime.h>

#define T_STEPS 25
#define BATCH   128
#define D_IN    2048
#define H_DIM   4096
#define C_DIM   1000
#define N_ALL   3200
#define GEMM_Q  320   // OpenBLAS SGEMM_DEFAULT_Q, SKYLAKEX path (verified bit-exact R7-R16)
#define P_K2048 7     // panels: 320x5, 224, 224
#define P_K4096 13    // panels: 320x11, 288, 288
#define WOT_LD  1024  // wo^T padded out-M (1000 -> 1024, pad rows zero)

typedef __attribute__((address_space(1))) const void gas_t;
typedef __attribute__((address_space(3))) void las_t;

// OpenBLAS level3 K-panel schedule (verified bit-exact R7):
__device__ __forceinline__ int panel_len(int rem) {
    return (rem >= 2 * GEMM_Q) ? GEMM_Q
         : (rem > GEMM_Q ? ((rem / 2 + 15) & ~15) : rem);
}

// ---------------- transpose (+optional mask premultiply, zero-pad): dst[K][MT] ----------------
// Mask entries are exactly 0/1, so w*m is the identical fp32 product the reference forms.
__global__ __launch_bounds__(256)
void tmask_k(float* __restrict__ dst, const float* __restrict__ src,
             const float* __restrict__ msk, int M, int K, int MT)
{
    __shared__ float t[32][33];
    const int tx = threadIdx.x, ty = threadIdx.y;
    const int k0 = blockIdx.x * 32, m0 = blockIdx.y * 32;
    #pragma unroll
    for (int i = 0; i < 4; ++i) {
        const int m = m0 + ty + 8 * i;
        float v = 0.f;
        if (m < M) {
            const size_t gi = (size_t)m * K + k0 + tx;
            v = src[gi];
            if (msk) v *= msk[gi];
        }
        t[ty + 8 * i][tx] = v;
    }
    __syncthreads();
    const int mc = m0 + tx;
    if (mc < MT) {
        #pragma unroll
        for (int i = 0; i < 4; ++i)
            dst[(size_t)(k0 + ty + 8 * i) * MT + mc] = t[tx][ty + 8 * i];
    }
}

// ---------------- barrier-free 1-wave per-panel GEMM: 16m x 128b, 4m x 8b per lane ----------------
// Lane map (C=8): cg = lane&15 -> cols cg*8..cg*8+7; mq = lane>>4 -> rows mq*4..mq*4+3.
// One ds_read_b128 (4 A rows) feeds 32 fmaf -> LDS pipe per CU-tile = 13x16x12 = 2496 cyc
// < VALU 3328 (R0's C=4 was 1.5x LDS-oversubscribed).
// B ping-pong with STATIC roles (bqA = kk0-7, bqB = kk8-15; never rotated -> no copies):
//   tile ti: issue bqB(ti) + stage(ti+1) -> vmcnt(17) [bqA(ti)+stage(ti) retired,
//            issued >=512cyc ago] -> compute kk0-7 -> issue bqA(ti+1) -> vmcnt(17)
//            [bqB(ti) retired] -> compute kk8-15.
// Every wait retires only loads covered by >=256 fmaf insts (512 cyc); the A stage is
// covered by ~2000 cyc. In-order vmcnt retirement makes 17 = 16 next-half loads + 1
// stage exact. NO sched_barrier: asm "memory" waits order memory ops (correctness for
// As; enforces 16-deep B flight) while leaving VALU scheduling free (R1's regression
// came from pinning the scheduler).
// part[p][m][b] = ascending-k fp32 fmaf chain over panel p from zero (exact OpenBLAS
// per-element ordering; cross-panel folds ascend in the reduce kernels).
#define FMA8(AS, R)                                                   \
    acc[R][0].x = fmaf(AS, bv0.x, acc[R][0].x);                       \
    acc[R][0].y = fmaf(AS, bv0.y, acc[R][0].y);                       \
    acc[R][0].z = fmaf(AS, bv0.z, acc[R][0].z);                       \
    acc[R][0].w = fmaf(AS, bv0.w, acc[R][0].w);                       \
    acc[R][1].x = fmaf(AS, bv1.x, acc[R][1].x);                       \
    acc[R][1].y = fmaf(AS, bv1.y, acc[R][1].y);                       \
    acc[R][1].z = fmaf(AS, bv1.z, acc[R][1].z);                       \
    acc[R][1].w = fmaf(AS, bv1.w, acc[R][1].w);

__global__ __launch_bounds__(64)
void gemm_w(const float* __restrict__ AT, const float* __restrict__ B,
            float* __restrict__ part, int MT, int K, int ldb, int n0)
{
#pragma clang fp reassociate(off)
    __shared__ __align__(16) float As[2][16][16];     // 2 KB, wave-private
    const int lane = threadIdx.x;                     // 0..63
    const int cg   = lane & 15;                       // col-group: 8 cols
    const int mq   = lane >> 4;                       // 0..3: 4 m-rows each
    const int m0   = blockIdx.y * 16;
    const int p    = blockIdx.x;

    int pstart = 0, rem = K, pl = panel_len(K);
    for (int i = 0; i < p; ++i) { pstart += pl; rem -= pl; pl = panel_len(rem); }
    const int nt = pl >> 4;                           // 320/288/224 all /16

    float4 acc[4][2];
    #pragma unroll
    for (int r = 0; r < 4; ++r) {
        acc[r][0] = make_float4(0.f, 0.f, 0.f, 0.f);
        acc[r][1] = make_float4(0.f, 0.f, 0.f, 0.f);
    }

    const float* bp = B + (size_t)pstart * ldb + n0 + cg * 8;
    // A stage lane-linear mapping, row-major [16k][16m]: (row lane>>2, col (lane&3)*4)
    const int akr = lane >> 2, amq = (lane & 3) * 4;
    const float* ap = AT + (size_t)(pstart + akr) * MT + m0 + amq;  // stage ptr, advances 16*MT/tile

    float4 bqA[16], bqB[16];

    // ---- prologue: stage tile 0, load bqA(0) ----
    __builtin_amdgcn_global_load_lds((gas_t*)ap, (las_t*)&As[0][0][0], 16, 0, 0);
    ap += (size_t)16 * MT;
    #pragma unroll
    for (int kk = 0; kk < 8; ++kk) {
        bqA[2 * kk]     = *(const float4*)(bp + (size_t)kk * ldb);
        bqA[2 * kk + 1] = *(const float4*)(bp + (size_t)kk * ldb + 4);
    }

    for (int ti = 0; ti < nt; ++ti) {
        const int bf = ti & 1;
        const bool more = (ti + 1 < nt);

        // ---- issue bqB(ti) + stage(ti+1); wait: bqA(ti)+stage(ti) retired ----
        #pragma unroll
        for (int kk = 0; kk < 8; ++kk) {
            bqB[2 * kk]     = *(const float4*)(bp + (size_t)(kk + 8) * ldb);
            bqB[2 * kk + 1] = *(const float4*)(bp + (size_t)(kk + 8) * ldb + 4);
        }
        if (more) {
            __builtin_amdgcn_global_load_lds((gas_t*)ap, (las_t*)&As[bf ^ 1][0][0], 16, 0, 0);
            ap += (size_t)16 * MT;
            asm volatile("s_waitcnt vmcnt(17)" ::: "memory");   // bqB(16)+stage(1) in flight
        } else {
            asm volatile("s_waitcnt vmcnt(16)" ::: "memory");   // bqB(16) in flight
        }
        #pragma unroll
        for (int kk = 0; kk < 8; ++kk) {
            const float4 av = *(const float4*)&As[bf][kk][mq * 4];
            const float4 bv0 = bqA[2 * kk], bv1 = bqA[2 * kk + 1];
            FMA8(av.x, 0) FMA8(av.y, 1) FMA8(av.z, 2) FMA8(av.w, 3)
        }

        // ---- issue bqA(ti+1); wait: bqB(ti) retired ----
        if (more) {
            #pragma unroll
            for (int kk = 0; kk < 8; ++kk) {
                bqA[2 * kk]     = *(const float4*)(bp + (size_t)(kk + 16) * ldb);
                bqA[2 * kk + 1] = *(const float4*)(bp + (size_t)(kk + 16) * ldb + 4);
            }
            asm volatile("s_waitcnt vmcnt(17)" ::: "memory");   // stage(1)+bqA(16) in flight
        } else {
            asm volatile("s_waitcnt vmcnt(0)" ::: "memory");
        }
        bp += (size_t)16 * ldb;
        #pragma unroll
        for (int kk = 8; kk < 16; ++kk) {
            const float4 av = *(const float4*)&As[bf][kk][mq * 4];
            const float4 bv0 = bqB[2 * (kk - 8)], bv1 = bqB[2 * (kk - 8) + 1];
            FMA8(av.x, 0) FMA8(av.y, 1) FMA8(av.z, 2) FMA8(av.w, 3)
        }
    }

    const int mrow0 = m0 + mq * 4;
    #pragma unroll
    for (int r = 0; r < 4; ++r) {
        *(float4*)&part[((size_t)p * MT + mrow0 + r) * BATCH + cg * 8]     = acc[r][0];
        *(float4*)&part[((size_t)p * MT + mrow0 + r) * BATCH + cg * 8 + 4] = acc[r][1];
    }
}

// ---------------- LIF (ops mirror np exactly; verified R7-R16) ----------------
__device__ __forceinline__ float lif1e(float c, float& m)
{
    const float r = (m > 1.0f) ? 1.0f : 0.0f;
    const float mn = __fsub_rn(__fadd_rn(__fmul_rn(0.95f, m), c), r);
    m = mn;
    return (mn > 1.0f) ? 1.0f : 0.0f;
}

// fold P panels ascending (one __fadd_rn each) + bias + LIF; float4 per thread
__global__ __launch_bounds__(256)
void reduce_lif4(const float* __restrict__ part, int P, int Mdim,
                 const float* __restrict__ bias, float* __restrict__ mem,
                 float* __restrict__ spk)
{
#pragma clang fp reassociate(off)
    const int idx4 = blockIdx.x * 256 + threadIdx.x;
    const int idx = idx4 * 4;
    const size_t stride = (size_t)Mdim * BATCH;
    float4 tot = *(const float4*)&part[idx];
    for (int z = 1; z < P; ++z) {
        const float4 pv = *(const float4*)&part[(size_t)z * stride + idx];
        tot.x = __fadd_rn(tot.x, pv.x); tot.y = __fadd_rn(tot.y, pv.y);
        tot.z = __fadd_rn(tot.z, pv.z); tot.w = __fadd_rn(tot.w, pv.w);
    }
    const float bb = bias[idx >> 7];
    float4 mm = *(float4*)&mem[idx];
    float4 sp;
    sp.x = lif1e(__fadd_rn(tot.x, bb), mm.x);
    sp.y = lif1e(__fadd_rn(tot.y, bb), mm.y);
    sp.z = lif1e(__fadd_rn(tot.z, bb), mm.z);
    sp.w = lif1e(__fadd_rn(tot.w, bb), mm.w);
    *(float4*)&mem[idx] = mm;
    *(float4*)&spk[idx] = sp;
}

// out-layer fold: partials are [P][Mpad][BATCH] (Mpad=1024 zero-padded); C_DIM rows live
__global__ __launch_bounds__(256)
void reduce_lif_out4(const float* __restrict__ part, int P, int Mpad,
                     const float* __restrict__ bias, float* __restrict__ mem,
                     float* __restrict__ out)
{
#pragma clang fp reassociate(off)
    const int idx4 = blockIdx.x * 256 + threadIdx.x;
    if (idx4 >= (C_DIM * BATCH) / 4) return;
    const int idx = idx4 * 4;
    const int cc = idx >> 7, b = idx & 127;
    const size_t stride = (size_t)Mpad * BATCH;
    float4 tot = *(const float4*)&part[idx];
    for (int z = 1; z < P; ++z) {
        const float4 pv = *(const float4*)&part[(size_t)z * stride + idx];
        tot.x = __fadd_rn(tot.x, pv.x); tot.y = __fadd_rn(tot.y, pv.y);
        tot.z = __fadd_rn(tot.z, pv.z); tot.w = __fadd_rn(tot.w, pv.w);
    }
    const float bb = bias[cc];
    float4 mm = *(float4*)&mem[idx];
    float s;
    s = lif1e(__fadd_rn(tot.x, bb), mm.x); if (s > 0.f) out[(size_t)(b+0) * C_DIM + cc] += 1.0f;
    s = lif1e(__fadd_rn(tot.y, bb), mm.y); if (s > 0.f) out[(size_t)(b+1) * C_DIM + cc] += 1.0f;
    s = lif1e(__fadd_rn(tot.z, bb), mm.z); if (s > 0.f) out[(size_t)(b+2) * C_DIM + cc] += 1.0f;
    s = lif1e(__fadd_rn(tot.w, bb), mm.w); if (s > 0.f) out[(size_t)(b+3) * C_DIM + cc] += 1.0f;
    *(float4*)&mem[idx] = mm;
}

// ---------------- host ----------------
extern "C" void kernel_launch(void* const* d_in, const int* in_sizes, int n_in,
                              void* d_out, int out_size, void* d_ws, size_t ws_size,
                              hipStream_t stream)
{
    const float* x  = (const float*)d_in[0];
    const float* w1 = (const float*)d_in[1];
    const float* b1 = (const float*)d_in[2];
    const float* m1 = (const float*)d_in[3];
    const float* w2 = (const float*)d_in[4];
    const float* b2 = (const float*)d_in[5];
    const float* m2 = (const float*)d_in[6];
    const float* w3 = (const float*)d_in[7];
    const float* b3 = (const float*)d_in[8];
    const float* m3 = (const float*)d_in[9];
    const float* wo = (const float*)d_in[10];
    const float* bo = (const float*)d_in[11];
    float* out = (float*)d_out;
    float* ws  = (float*)d_ws;
    (void)in_sizes; (void)n_in; (void)ws_size;

    const size_t HB = (size_t)H_DIM * BATCH;        // 524288
    const size_t CB = (size_t)C_DIM * BATCH;        // 128000

    // ---- ws layout (floats) — total ≈ 252 MB (verified fits R12-R16) ----
    size_t off = 0;
    const size_t MEM1 = off; off += HB;
    const size_t MEM2 = off; off += HB;
    const size_t MEM3 = off; off += HB;
    const size_t MEMO = off; off += CB;
    const size_t stateFloats = off;                 // zeroed every call
    const size_t SPK1 = off; off += HB;
    const size_t SPK2 = off; off += HB;
    const size_t SPK3 = off; off += HB;
    const size_t PART = off; off += (size_t)P_K4096 * HB;       // 13 x [4096][128]
    const size_t EWT1 = off; off += (size_t)D_IN * H_DIM;       // [2048][4096]
    const size_t EWT2 = off; off += (size_t)H_DIM * H_DIM;      // [4096][4096]
    const size_t EWT3 = off; off += (size_t)H_DIM * H_DIM;
    const size_t WOT  = off; off += (size_t)H_DIM * WOT_LD;     // [4096][1024]
    const size_t XT   = off; off += (size_t)D_IN * N_ALL;       // [2048][3200]

    hipMemsetAsync(d_ws, 0, stateFloats * sizeof(float), stream);
    hipMemsetAsync(d_out, 0, (size_t)out_size * sizeof(float), stream);

    // ---- one-time transposes (premask fused; bit-exact products) ----
    {
        dim3 tb(32, 8);
        tmask_k<<<dim3(D_IN / 32, H_DIM / 32), tb, 0, stream>>>(ws + EWT1, w1, m1, H_DIM, D_IN, H_DIM);
        tmask_k<<<dim3(H_DIM / 32, H_DIM / 32), tb, 0, stream>>>(ws + EWT2, w2, m2, H_DIM, H_DIM, H_DIM);
        tmask_k<<<dim3(H_DIM / 32, H_DIM / 32), tb, 0, stream>>>(ws + EWT3, w3, m3, H_DIM, H_DIM, H_DIM);
        tmask_k<<<dim3(H_DIM / 32, WOT_LD / 32), tb, 0, stream>>>(ws + WOT, wo, nullptr, C_DIM, H_DIM, WOT_LD);
        tmask_k<<<dim3(D_IN / 32, N_ALL / 32), tb, 0, stream>>>(ws + XT, x, nullptr, N_ALL, D_IN, N_ALL);
    }

    const dim3 g1(P_K2048, H_DIM / 16);             // 7 x 256 = 1792 one-wave blocks
    const dim3 g23(P_K4096, H_DIM / 16);            // 13 x 256 = 3328
    const dim3 go(P_K4096, WOT_LD / 16);            // 13 x 64 = 832
    const int gLif4  = (int)(HB / 4 / 256);         // 512
    const int gLifO4 = (int)((CB / 4 + 255) / 256); // 125

    for (int t = 0; t < T_STEPS; ++t) {
        // layer 1: AT = EWT1 [2048][4096], B = XT [2048][3200] cols t*128..
        gemm_w<<<g1, 64, 0, stream>>>(ws + EWT1, ws + XT, ws + PART,
                                      H_DIM, D_IN, N_ALL, t * BATCH);
        reduce_lif4<<<gLif4, 256, 0, stream>>>(ws + PART, P_K2048, H_DIM, b1, ws + MEM1, ws + SPK1);

        // layer 2
        gemm_w<<<g23, 64, 0, stream>>>(ws + EWT2, ws + SPK1, ws + PART,
                                       H_DIM, H_DIM, BATCH, 0);
        reduce_lif4<<<gLif4, 256, 0, stream>>>(ws + PART, P_K4096, H_DIM, b2, ws + MEM2, ws + SPK2);

        // layer 3
        gemm_w<<<g23, 64, 0, stream>>>(ws + EWT3, ws + SPK2, ws + PART,
                                       H_DIM, H_DIM, BATCH, 0);
        reduce_lif4<<<gLif4, 256, 0, stream>>>(ws + PART, P_K4096, H_DIM, b3, ws + MEM3, ws + SPK3);

        // output layer (WOT zero-padded to 1024 rows)
        gemm_w<<<go, 64, 0, stream>>>(ws + WOT, ws + SPK3, ws + PART,
                                      WOT_LD, H_DIM, BATCH, 0);
        reduce_lif_out4<<<gLifO4, 256, 0, stream>>>(ws + PART, P_K4096, WOT_LD, bo, ws + MEMO, out);
    }
}

// Round 6
// 5195.256 us; speedup vs baseline: 1.5861x; 1.5861x over previous
//
#include <hip/hip_runtime.h>

#define T_STEPS 25
#define BATCH   128
#define D_IN    2048
#define H_DIM   4096
#define C_DIM   1000
#define N_ALL   3200
#define GEMM_Q  320   // OpenBLAS SGEMM_DEFAULT_Q, SKYLAKEX path (verified bit-exact R7-R16)
#define P_K2048 7     // panels: 320x5, 224, 224
#define P_K4096 13    // panels: 320x11, 288, 288
#define WOT_LD  1024  // wo^T padded out-M (1000 -> 1024, pad rows zero)

typedef __attribute__((address_space(1))) const void gas_t;
typedef __attribute__((address_space(3))) void las_t;

// OpenBLAS level3 K-panel schedule (verified bit-exact R7):
__device__ __forceinline__ int panel_len(int rem) {
    return (rem >= 2 * GEMM_Q) ? GEMM_Q
         : (rem > GEMM_Q ? ((rem / 2 + 15) & ~15) : rem);
}

// ---------------- transpose (+optional mask premultiply, zero-pad): dst[K][MT] ----------------
// Mask entries are exactly 0/1, so w*m is the identical fp32 product the reference forms.
__global__ __launch_bounds__(256)
void tmask_k(float* __restrict__ dst, const float* __restrict__ src,
             const float* __restrict__ msk, int M, int K, int MT)
{
    __shared__ float t[32][33];
    const int tx = threadIdx.x, ty = threadIdx.y;
    const int k0 = blockIdx.x * 32, m0 = blockIdx.y * 32;
    #pragma unroll
    for (int i = 0; i < 4; ++i) {
        const int m = m0 + ty + 8 * i;
        float v = 0.f;
        if (m < M) {
            const size_t gi = (size_t)m * K + k0 + tx;
            v = src[gi];
            if (msk) v *= msk[gi];
        }
        t[ty + 8 * i][tx] = v;
    }
    __syncthreads();
    const int mc = m0 + tx;
    if (mc < MT) {
        #pragma unroll
        for (int i = 0; i < 4; ++i)
            dst[(size_t)(k0 + ty + 8 * i) * MT + mc] = t[tx][ty + 8 * i];
    }
}

// ---------------- 4-wave shared-B GEMM: block = 64m x 128b, wave = 16m, lane = 8m x 4b ----------------
// R0's verified-exact per-lane arithmetic (C=4 map: mg = lane>>5 m-half, lc = lane&31
// col-quad; ascending-k fmaf chains) with ONE structural change: the 16k x 128col B
// tile (8KB) is staged ONCE per 4-wave block into shared LDS (8 global_load_lds, 2 per
// wave) instead of privately per wave (R0: 16 dwordx4 per wave, duplicated lanes).
// Rationale: R0-R4 tile-round time tracks VMEM insts/CU at ~40cyc/inst (221->9600cyc,
// 429->16200, 508->16900); this cuts insts/CU/round 221 -> 39 (3.25 blocks x 12) and
// per-CU request bytes by the same 5.7x. B values pass through LDS bit-unmodified and
// the fmaf order per output is untouched -> bit-exact vs OpenBLAS reference.
// Cadence per tile: [stage A(ti+1)+B(ti+1) -> buf^1 (3 insts/wave)] [compute ti from
// buf] [__syncthreads: vmcnt(0) drains staging (issued ~1400cyc earlier, cheap) +
// barrier]. Buffer safety: stage(ti+2) overwrites buf only after the sync that follows
// its last reader. part[p][m][b] = ascending-k fmaf chain per panel from zero;
// cross-panel folds ascend in the reduce kernels.
#define FMAQ(AS, R)                                                   \
    acc[R].x = fmaf(AS, bv.x, acc[R].x);                              \
    acc[R].y = fmaf(AS, bv.y, acc[R].y);                              \
    acc[R].z = fmaf(AS, bv.z, acc[R].z);                              \
    acc[R].w = fmaf(AS, bv.w, acc[R].w);

__global__ __launch_bounds__(256)
void gemm_w(const float* __restrict__ AT, const float* __restrict__ B,
            float* __restrict__ part, int MT, int K, int ldb, int n0)
{
#pragma clang fp reassociate(off)
    __shared__ __align__(16) float Bs[2][16][128];    // 16 KB block-shared B tile (dbuf)
    __shared__ __align__(16) float As[4][2][16][16];  // 8 KB wave-private A tiles (dbuf)
    const int tid  = threadIdx.x;
    const int w    = tid >> 6;                        // wave 0..3
    const int lane = tid & 63;
    const int mg   = lane >> 5;                       // 0/1: m-half within wave tile
    const int lc   = lane & 31;                       // b-col quad
    const int m0   = blockIdx.y * 64 + w * 16;        // wave's 16-row m tile
    const int p    = blockIdx.x;

    int pstart = 0, rem = K, pl = panel_len(K);
    for (int i = 0; i < p; ++i) { pstart += pl; rem -= pl; pl = panel_len(rem); }
    const int nt = pl >> 4;                           // 320/288/224 all /16

    float4 acc[8];
    #pragma unroll
    for (int r = 0; r < 8; ++r) acc[r] = make_float4(0.f, 0.f, 0.f, 0.f);

    // A stage (per wave, as R0): lane l -> (k-row l>>2, m-quad l&3); dest lane-linear
    const int akr = lane >> 2, amq = (lane & 3) * 4;
    const float* ap = AT + (size_t)(pstart + akr) * MT + m0 + amq;
    // B stage (block-cooperative): wave w covers rows w*4..w*4+3 via 2 insts;
    // inst i: lanes 0-31 -> row w*4+2i col lc*4, lanes 32-63 -> row w*4+2i+1
    const float* bsrc = B + (size_t)(pstart + w * 4 + (lane >> 5)) * ldb + n0 + lc * 4;

    {   // prologue: stage tile 0
        __builtin_amdgcn_global_load_lds((gas_t*)ap, (las_t*)&As[w][0][0][0], 16, 0, 0);
        __builtin_amdgcn_global_load_lds((gas_t*)bsrc,
                                         (las_t*)&Bs[0][w * 4][0], 16, 0, 0);
        __builtin_amdgcn_global_load_lds((gas_t*)(bsrc + 2 * (size_t)ldb),
                                         (las_t*)&Bs[0][w * 4 + 2][0], 16, 0, 0);
    }
    __syncthreads();

    for (int ti = 0; ti < nt; ++ti) {
        const int bf = ti & 1;
        // ---- stage tile ti+1 into buf^1 (3 insts/wave; lands before the sync) ----
        if (ti + 1 < nt) {
            const float* a2 = ap + (size_t)(ti + 1) * 16 * MT;
            const float* b2 = bsrc + (size_t)(ti + 1) * 16 * ldb;
            __builtin_amdgcn_global_load_lds((gas_t*)a2, (las_t*)&As[w][bf ^ 1][0][0], 16, 0, 0);
            __builtin_amdgcn_global_load_lds((gas_t*)b2,
                                             (las_t*)&Bs[bf ^ 1][w * 4][0], 16, 0, 0);
            __builtin_amdgcn_global_load_lds((gas_t*)(b2 + 2 * (size_t)ldb),
                                             (las_t*)&Bs[bf ^ 1][w * 4 + 2][0], 16, 0, 0);
        }
        // ---- compute tile ti: 16 ascending k-steps, 32 fmaf chains per lane ----
        #pragma unroll
        for (int kk = 0; kk < 16; ++kk) {
            const float4 a0 = *(const float4*)&As[w][bf][kk][mg * 8];
            const float4 a1 = *(const float4*)&As[w][bf][kk][mg * 8 + 4];
            const float4 bv = *(const float4*)&Bs[bf][kk][lc * 4];
            FMAQ(a0.x, 0) FMAQ(a0.y, 1) FMAQ(a0.z, 2) FMAQ(a0.w, 3)
            FMAQ(a1.x, 4) FMAQ(a1.y, 5) FMAQ(a1.z, 6) FMAQ(a1.w, 7)
        }
        // vmcnt(0)+lgkmcnt(0)+barrier: staging(ti+1) landed; all waves done reading buf
        __syncthreads();
    }

    const int mrow0 = m0 + mg * 8;
    #pragma unroll
    for (int r = 0; r < 8; ++r)
        *(float4*)&part[((size_t)p * MT + mrow0 + r) * BATCH + lc * 4] = acc[r];
}

// ---------------- LIF (ops mirror np exactly; verified R7-R16) ----------------
__device__ __forceinline__ float lif1e(float c, float& m)
{
    const float r = (m > 1.0f) ? 1.0f : 0.0f;
    const float mn = __fsub_rn(__fadd_rn(__fmul_rn(0.95f, m), c), r);
    m = mn;
    return (mn > 1.0f) ? 1.0f : 0.0f;
}

// fold P panels ascending (one __fadd_rn each) + bias + LIF; float4 per thread
__global__ __launch_bounds__(256)
void reduce_lif4(const float* __restrict__ part, int P, int Mdim,
                 const float* __restrict__ bias, float* __restrict__ mem,
                 float* __restrict__ spk)
{
#pragma clang fp reassociate(off)
    const int idx4 = blockIdx.x * 256 + threadIdx.x;
    const int idx = idx4 * 4;
    const size_t stride = (size_t)Mdim * BATCH;
    float4 tot = *(const float4*)&part[idx];
    for (int z = 1; z < P; ++z) {
        const float4 pv = *(const float4*)&part[(size_t)z * stride + idx];
        tot.x = __fadd_rn(tot.x, pv.x); tot.y = __fadd_rn(tot.y, pv.y);
        tot.z = __fadd_rn(tot.z, pv.z); tot.w = __fadd_rn(tot.w, pv.w);
    }
    const float bb = bias[idx >> 7];
    float4 mm = *(float4*)&mem[idx];
    float4 sp;
    sp.x = lif1e(__fadd_rn(tot.x, bb), mm.x);
    sp.y = lif1e(__fadd_rn(tot.y, bb), mm.y);
    sp.z = lif1e(__fadd_rn(tot.z, bb), mm.z);
    sp.w = lif1e(__fadd_rn(tot.w, bb), mm.w);
    *(float4*)&mem[idx] = mm;
    *(float4*)&spk[idx] = sp;
}

// out-layer fold: partials are [P][Mpad][BATCH] (Mpad=1024 zero-padded); C_DIM rows live
__global__ __launch_bounds__(256)
void reduce_lif_out4(const float* __restrict__ part, int P, int Mpad,
                     const float* __restrict__ bias, float* __restrict__ mem,
                     float* __restrict__ out)
{
#pragma clang fp reassociate(off)
    const int idx4 = blockIdx.x * 256 + threadIdx.x;
    if (idx4 >= (C_DIM * BATCH) / 4) return;
    const int idx = idx4 * 4;
    const int cc = idx >> 7, b = idx & 127;
    const size_t stride = (size_t)Mpad * BATCH;
    float4 tot = *(const float4*)&part[idx];
    for (int z = 1; z < P; ++z) {
        const float4 pv = *(const float4*)&part[(size_t)z * stride + idx];
        tot.x = __fadd_rn(tot.x, pv.x); tot.y = __fadd_rn(tot.y, pv.y);
        tot.z = __fadd_rn(tot.z, pv.z); tot.w = __fadd_rn(tot.w, pv.w);
    }
    const float bb = bias[cc];
    float4 mm = *(float4*)&mem[idx];
    float s;
    s = lif1e(__fadd_rn(tot.x, bb), mm.x); if (s > 0.f) out[(size_t)(b+0) * C_DIM + cc] += 1.0f;
    s = lif1e(__fadd_rn(tot.y, bb), mm.y); if (s > 0.f) out[(size_t)(b+1) * C_DIM + cc] += 1.0f;
    s = lif1e(__fadd_rn(tot.z, bb), mm.z); if (s > 0.f) out[(size_t)(b+2) * C_DIM + cc] += 1.0f;
    s = lif1e(__fadd_rn(tot.w, bb), mm.w); if (s > 0.f) out[(size_t)(b+3) * C_DIM + cc] += 1.0f;
    *(float4*)&mem[idx] = mm;
}

// ---------------- host ----------------
extern "C" void kernel_launch(void* const* d_in, const int* in_sizes, int n_in,
                              void* d_out, int out_size, void* d_ws, size_t ws_size,
                              hipStream_t stream)
{
    const float* x  = (const float*)d_in[0];
    const float* w1 = (const float*)d_in[1];
    const float* b1 = (const float*)d_in[2];
    const float* m1 = (const float*)d_in[3];
    const float* w2 = (const float*)d_in[4];
    const float* b2 = (const float*)d_in[5];
    const float* m2 = (const float*)d_in[6];
    const float* w3 = (const float*)d_in[7];
    const float* b3 = (const float*)d_in[8];
    const float* m3 = (const float*)d_in[9];
    const float* wo = (const float*)d_in[10];
    const float* bo = (const float*)d_in[11];
    float* out = (float*)d_out;
    float* ws  = (float*)d_ws;
    (void)in_sizes; (void)n_in; (void)ws_size;

    const size_t HB = (size_t)H_DIM * BATCH;        // 524288
    const size_t CB = (size_t)C_DIM * BATCH;        // 128000

    // ---- ws layout (floats) — total ≈ 252 MB (verified fits R12-R16) ----
    size_t off = 0;
    const size_t MEM1 = off; off += HB;
    const size_t MEM2 = off; off += HB;
    const size_t MEM3 = off; off += HB;
    const size_t MEMO = off; off += CB;
    const size_t stateFloats = off;                 // zeroed every call
    const size_t SPK1 = off; off += HB;
    const size_t SPK2 = off; off += HB;
    const size_t SPK3 = off; off += HB;
    const size_t PART = off; off += (size_t)P_K4096 * HB;       // 13 x [4096][128]
    const size_t EWT1 = off; off += (size_t)D_IN * H_DIM;       // [2048][4096]
    const size_t EWT2 = off; off += (size_t)H_DIM * H_DIM;      // [4096][4096]
    const size_t EWT3 = off; off += (size_t)H_DIM * H_DIM;
    const size_t WOT  = off; off += (size_t)H_DIM * WOT_LD;     // [4096][1024]
    const size_t XT   = off; off += (size_t)D_IN * N_ALL;       // [2048][3200]

    hipMemsetAsync(d_ws, 0, stateFloats * sizeof(float), stream);
    hipMemsetAsync(d_out, 0, (size_t)out_size * sizeof(float), stream);

    // ---- one-time transposes (premask fused; bit-exact products) ----
    {
        dim3 tb(32, 8);
        tmask_k<<<dim3(D_IN / 32, H_DIM / 32), tb, 0, stream>>>(ws + EWT1, w1, m1, H_DIM, D_IN, H_DIM);
        tmask_k<<<dim3(H_DIM / 32, H_DIM / 32), tb, 0, stream>>>(ws + EWT2, w2, m2, H_DIM, H_DIM, H_DIM);
        tmask_k<<<dim3(H_DIM / 32, H_DIM / 32), tb, 0, stream>>>(ws + EWT3, w3, m3, H_DIM, H_DIM, H_DIM);
        tmask_k<<<dim3(H_DIM / 32, WOT_LD / 32), tb, 0, stream>>>(ws + WOT, wo, nullptr, C_DIM, H_DIM, WOT_LD);
        tmask_k<<<dim3(D_IN / 32, N_ALL / 32), tb, 0, stream>>>(ws + XT, x, nullptr, N_ALL, D_IN, N_ALL);
    }

    const dim3 g1(P_K2048, H_DIM / 64);             // 7 x 64 = 448 4-wave blocks
    const dim3 g23(P_K4096, H_DIM / 64);            // 13 x 64 = 832 4-wave blocks
    const dim3 go(P_K4096, WOT_LD / 64);            // 13 x 16 = 208 4-wave blocks
    const int gLif4  = (int)(HB / 4 / 256);         // 512
    const int gLifO4 = (int)((CB / 4 + 255) / 256); // 125

    for (int t = 0; t < T_STEPS; ++t) {
        // layer 1: AT = EWT1 [2048][4096], B = XT [2048][3200] cols t*128..
        gemm_w<<<g1, 256, 0, stream>>>(ws + EWT1, ws + XT, ws + PART,
                                       H_DIM, D_IN, N_ALL, t * BATCH);
        reduce_lif4<<<gLif4, 256, 0, stream>>>(ws + PART, P_K2048, H_DIM, b1, ws + MEM1, ws + SPK1);

        // layer 2
        gemm_w<<<g23, 256, 0, stream>>>(ws + EWT2, ws + SPK1, ws + PART,
                                        H_DIM, H_DIM, BATCH, 0);
        reduce_lif4<<<gLif4, 256, 0, stream>>>(ws + PART, P_K4096, H_DIM, b2, ws + MEM2, ws + SPK2);

        // layer 3
        gemm_w<<<g23, 256, 0, stream>>>(ws + EWT3, ws + SPK2, ws + PART,
                                        H_DIM, H_DIM, BATCH, 0);
        reduce_lif4<<<gLif4, 256, 0, stream>>>(ws + PART, P_K4096, H_DIM, b3, ws + MEM3, ws + SPK3);

        // output layer (WOT zero-padded to 1024 rows)
        gemm_w<<<go, 256, 0, stream>>>(ws + WOT, ws + SPK3, ws + PART,
                                       WOT_LD, H_DIM, BATCH, 0);
        reduce_lif_out4<<<gLifO4, 256, 0, stream>>>(ws + PART, P_K4096, WOT_LD, bo, ws + MEMO, out);
    }
}